// Round 1
// baseline (85.081 us; speedup 1.0000x reference)
//
#include <hip/hip_runtime.h>

// ConvCapsLayer: A=32,B=32,K=3,P=4,STRIDE=2,ITERS=3 — fp32 in/out
// x: (2,32,32,512) f32   weights: (288,32,16) f32   out: (450,512) f32
//
// R14 = R11 structure + cross-lane surgery. One WAVE per (n, j), 64-thr
// blocks; lane owns i = lane+64k, k=0..4 (k=4 only lane<32); v[5][8]
// packed v2f in registers; bf16-staged inputs:
//   xt_bf[pixel][a][16]  (4 MB, cast)     wt_bf[j][k][lane][16] (320 KB)
// Unnormalized softmax (SE rides butterfly), split-first butterfly.
// R14 change (data-movement only, arithmetic bit-identical to R11):
//   xor1/xor2  -> DPP quad_perm (VALU pipe, ~4cy dep latency)
//   xor4/8/16  -> ds_swizzle imm (1 DS op, no addr calc)
//   xor32      -> __shfl_xor (kept; ~2/iter, negligible)
//   p-broadcast: 16x __shfl -> 16x v_readlane into SGPRs (p[q] identical
//     at lanes q,q+16,q+32,q+48); dot consumes p as scalar operands.
//     Deletes p[16]/p2[8] VGPR arrays.
// Probed and rejected: 4-wave blocks w/ LDS x-stage (R12, +3.4µs), 2-j ILP
// (R7, neutral), recompute-v (R10, spill), tighter launch bounds (R4, spill).
// LESSON (R4, R10): live set ~84 VGPR. Never bound/structure below it.
// Budget: dur = ~48µs harness d_ws-poison fill (81% HBM peak, untouchable)
//             + ~4µs staging + main (latency plateau, attacking DS chains).

#define OH 15
#define OW 15
#define EPS_ 1e-8f

#define XT_ELEMS (2 * 32 * 32 * 512)        // 2,097,152 bf16 (4 MB)
#define WT_ELEMS (32 * 5 * 64 * 16)         // 163,840 bf16 (320 KB)

typedef float v2f __attribute__((ext_vector_type(2)));

__device__ __forceinline__ v2f pfma(float a, v2f b, v2f c) {
    return __builtin_elementwise_fma((v2f){a, a}, b, c);
}
__device__ __forceinline__ float b_lo(unsigned int u) {
    union { unsigned int i; float f; } c; c.i = u << 16; return c.f;
}
__device__ __forceinline__ float b_hi(unsigned int u) {
    union { unsigned int i; float f; } c; c.i = u & 0xFFFF0000u; return c.f;
}
__device__ __forceinline__ unsigned short f2bf(float f) {
    union { float f; unsigned int i; } c; c.f = f;
    return (unsigned short)((c.i + 0x7FFFu + ((c.i >> 16) & 1u)) >> 16); // RNE
}

// ---- cross-lane helpers (movement only; no arithmetic change) ----
// DPP quad_perm[1,0,3,2] = xor1 ; quad_perm[2,3,0,1] = xor2
__device__ __forceinline__ float dppx1(float x) {
    return __builtin_bit_cast(float, __builtin_amdgcn_update_dpp(
        0, __builtin_bit_cast(int, x), 0xB1, 0xF, 0xF, true));
}
__device__ __forceinline__ float dppx2(float x) {
    return __builtin_bit_cast(float, __builtin_amdgcn_update_dpp(
        0, __builtin_bit_cast(int, x), 0x4E, 0xF, 0xF, true));
}
// ds_swizzle BitMode: offset = (xor<<10)|(or<<5)|and, and=0x1F
// 0x101F = xor4, 0x201F = xor8, 0x401F = xor16 (bit4 flip stays in-half)
template <int OFF>
__device__ __forceinline__ float swzx(float x) {
    return __builtin_bit_cast(float, __builtin_amdgcn_ds_swizzle(
        __builtin_bit_cast(int, x), OFF));
}
__device__ __forceinline__ float rdlane(float x, int q) {
    return __builtin_bit_cast(float, __builtin_amdgcn_readlane(
        __builtin_bit_cast(int, x), q));
}

// merged staging: [0, XT_ELEMS) casts x; [XT_ELEMS, +WT_ELEMS) permutes w
__global__ __launch_bounds__(256) void stage_kernel(
    const float* __restrict__ x, const float* __restrict__ w,
    unsigned short* __restrict__ xt, unsigned short* __restrict__ wt)
{
    const int tid = blockIdx.x * 256 + threadIdx.x;
    if (tid < XT_ELEMS) {
        xt[tid] = f2bf(x[tid]);
    } else {
        const int t2 = tid - XT_ELEMS;      // over WT_ELEMS
        const int j  = t2 / 5120;
        const int r  = t2 - j * 5120;
        const int k  = r >> 10;
        const int L  = (r >> 4) & 63;
        const int e  = r & 15;
        const int i  = L + 64 * k;
        wt[t2] = (i < 288) ? f2bf(w[(size_t)i * 512 + j * 16 + e])
                           : (unsigned short)0;
    }
}

template <bool PERM>
__global__ __launch_bounds__(64, 3) void convcaps_kernel(
    const void* __restrict__ xp,   // PERM ? bf16 xt : f32 x
    const void* __restrict__ wp_,  // PERM ? bf16 wt : f32 w
    float* __restrict__ out)       // (450,512)
{
    const int blk  = blockIdx.x;      // 0..14399
    const int n    = blk >> 5;        // patch 0..449
    const int j    = blk & 31;        // out capsule
    const int lane = threadIdx.x;     // 0..63

    const int batch = n / (OH * OW);
    const int rem   = n - batch * OH * OW;
    const int oy    = rem / OW;
    const int ox    = rem - oy * OW;

    const bool has5 = (lane < 32);

    v2f v[5][8];                      // v[k][p*2+qq]
    // inactive 5th slot: logit = -inf so exp -> 0 (drops has5 selects later)
    float logit[5] = {0.f, 0.f, 0.f, 0.f, has5 ? 0.f : -1e30f};

    // ---- v[k] = X_i(4x4) * W_ij(4x4), i = lane + 64k ----
#pragma unroll
    for (int k = 0; k < 5; ++k) {
        if (k == 4 && !has5) {
#pragma unroll
            for (int m = 0; m < 8; ++m) v[4][m] = (v2f){0.f, 0.f};
        } else {
            const int i  = lane + 64 * k;
            const int a  = i & 31;
            const int kw = (i >> 5) % 3;
            const int kh = i / 96;
            const int h  = oy * 2 + kh;
            const int wc = ox * 2 + kw;
            const int pixel = (batch * 32 + h) * 32 + wc;

            float xr[16];
            v2f wr2[4][2];
            if (PERM) {
                // xt[pixel][a][16] bf16: 32B contiguous per lane
                const uint4* xb = reinterpret_cast<const uint4*>(
                    (const unsigned short*)xp + ((size_t)pixel * 512 + a * 16));
                uint4 u0 = xb[0], u1 = xb[1];
                xr[0]=b_lo(u0.x); xr[1]=b_hi(u0.x); xr[2]=b_lo(u0.y); xr[3]=b_hi(u0.y);
                xr[4]=b_lo(u0.z); xr[5]=b_hi(u0.z); xr[6]=b_lo(u0.w); xr[7]=b_hi(u0.w);
                xr[8]=b_lo(u1.x); xr[9]=b_hi(u1.x); xr[10]=b_lo(u1.y); xr[11]=b_hi(u1.y);
                xr[12]=b_lo(u1.z); xr[13]=b_hi(u1.z); xr[14]=b_lo(u1.w); xr[15]=b_hi(u1.w);
                // wt[j][k][lane][16] bf16: 32B contiguous per lane
                const uint4* wb = reinterpret_cast<const uint4*>(
                    (const unsigned short*)wp_ + (((size_t)j * 5 + k) * 64 + lane) * 16);
                uint4 q0 = wb[0], q1 = wb[1];
                wr2[0][0] = (v2f){b_lo(q0.x), b_hi(q0.x)};
                wr2[0][1] = (v2f){b_lo(q0.y), b_hi(q0.y)};
                wr2[1][0] = (v2f){b_lo(q0.z), b_hi(q0.z)};
                wr2[1][1] = (v2f){b_lo(q0.w), b_hi(q0.w)};
                wr2[2][0] = (v2f){b_lo(q1.x), b_hi(q1.x)};
                wr2[2][1] = (v2f){b_lo(q1.y), b_hi(q1.y)};
                wr2[3][0] = (v2f){b_lo(q1.z), b_hi(q1.z)};
                wr2[3][1] = (v2f){b_lo(q1.w), b_hi(q1.w)};
            } else {
                const float4* xv = reinterpret_cast<const float4*>(
                    (const float*)xp + ((size_t)pixel * 512 + a * 16));
                float4 x0 = xv[0], x1 = xv[1], x2 = xv[2], x3 = xv[3];
                float t_[16] = { x0.x,x0.y,x0.z,x0.w, x1.x,x1.y,x1.z,x1.w,
                                 x2.x,x2.y,x2.z,x2.w, x3.x,x3.y,x3.z,x3.w };
#pragma unroll
                for (int e = 0; e < 16; ++e) xr[e] = t_[e];
                const float4* wq = reinterpret_cast<const float4*>(
                    (const float*)wp_ + ((size_t)i * 32 + j) * 16);
                float4 w0 = wq[0], w1 = wq[1], w2 = wq[2], w3 = wq[3];
                wr2[0][0]=(v2f){w0.x,w0.y}; wr2[0][1]=(v2f){w0.z,w0.w};
                wr2[1][0]=(v2f){w1.x,w1.y}; wr2[1][1]=(v2f){w1.z,w1.w};
                wr2[2][0]=(v2f){w2.x,w2.y}; wr2[2][1]=(v2f){w2.z,w2.w};
                wr2[3][0]=(v2f){w3.x,w3.y}; wr2[3][1]=(v2f){w3.z,w3.w};
            }

#pragma unroll
            for (int p = 0; p < 4; ++p) {
#pragma unroll
                for (int qq = 0; qq < 2; ++qq) {
                    v2f acc = (v2f){0.f, 0.f};
                    acc = pfma(xr[p*4+0], wr2[0][qq], acc);
                    acc = pfma(xr[p*4+1], wr2[1][qq], acc);
                    acc = pfma(xr[p*4+2], wr2[2][qq], acc);
                    acc = pfma(xr[p*4+3], wr2[3][qq], acc);
                    v[k][p*2+qq] = acc;
                }
            }
        }
    }

#pragma unroll
    for (int it = 0; it < 3; ++it) {
        v2f c2[8];
        float se_loc;
        if (it == 0) {
#pragma unroll
            for (int m = 0; m < 8; ++m)
                c2[m] = v[0][m] + v[1][m] + v[2][m] + v[3][m] + v[4][m];
            se_loc = 0.f;  // normalizer is 288 (softmax of zeros)
        } else {
            const float e0 = __expf(logit[0]), e1 = __expf(logit[1]);
            const float e2 = __expf(logit[2]), e3 = __expf(logit[3]);
            const float e4 = __expf(logit[4]);   // 0 for lanes >= 32
#pragma unroll
            for (int m = 0; m < 8; ++m)
                c2[m] = pfma(e0, v[0][m],
                        pfma(e1, v[1][m],
                        pfma(e2, v[2][m],
                        pfma(e3, v[3][m],
                        pfma(e4, v[4][m], (v2f){0.f, 0.f})))));
            se_loc = e0 + e1 + e2 + e3 + e4;
        }

        float c[16];
#pragma unroll
        for (int m = 0; m < 8; ++m) { c[2*m] = c2[m].x; c[2*m+1] = c2[m].y; }

        // ---- split-first butterfly: comp bit b -> lane bit b ----
        // levels 1,2 on DPP (VALU); 4,8,16 on ds_swizzle; 32 on shfl.
        float seR = se_loc;
        float s8[8];
        {
            const bool b = lane & 1;
#pragma unroll
            for (int m = 0; m < 8; ++m) {
                float send = b ? c[2*m]   : c[2*m+1];
                float keep = b ? c[2*m+1] : c[2*m];
                s8[m] = keep + dppx1(send);
            }
            if (it > 0) seR += dppx1(seR);
        }
        float s4[4];
        {
            const bool b = (lane >> 1) & 1;
#pragma unroll
            for (int m = 0; m < 4; ++m) {
                float send = b ? s8[2*m]   : s8[2*m+1];
                float keep = b ? s8[2*m+1] : s8[2*m];
                s4[m] = keep + dppx2(send);
            }
            if (it > 0) seR += dppx2(seR);
        }
        float s2v[2];
        {
            const bool b = (lane >> 2) & 1;
#pragma unroll
            for (int m = 0; m < 2; ++m) {
                float send = b ? s4[2*m]   : s4[2*m+1];
                float keep = b ? s4[2*m+1] : s4[2*m];
                s2v[m] = keep + swzx<0x101F>(send);
            }
            if (it > 0) seR += swzx<0x101F>(seR);
        }
        float s1;
        {
            const bool b = (lane >> 3) & 1;
            float send = b ? s2v[0] : s2v[1];
            float keep = b ? s2v[1] : s2v[0];
            s1 = keep + swzx<0x201F>(send);
            if (it > 0) seR += swzx<0x201F>(seR);
        }
        s1 += swzx<0x401F>(s1);    if (it > 0) seR += swzx<0x401F>(seR);
        s1 += __shfl_xor(s1, 32);  if (it > 0) seR += __shfl_xor(seR, 32);
        // s1 = sum_i (e_i or 1) * v_i[comp], comp = lane&15 ; seR = SE

        const float s = (it == 0) ? s1 * (1.0f / 288.0f) : s1 / seR;

        // ---- squash ----
        float t2 = s * s;
        t2 += dppx1(t2);
        t2 += dppx2(t2);
        t2 += swzx<0x101F>(t2);
        t2 += swzx<0x201F>(t2);
        const float n2 = t2;
        const float scale = n2 / ((1.0f + n2) * sqrtf(n2 + EPS_));
        const float pval = s * scale;   // comp (lane&15) of p

        if (it < 2) {
            // p[q] identical at lanes q, q+16, q+32, q+48 -> readlane(q),
            // lands in SGPRs; dot consumes p as scalar fma operands.
            float pq[16];
#pragma unroll
            for (int q = 0; q < 16; ++q) pq[q] = rdlane(pval, q);
#pragma unroll
            for (int k = 0; k < 5; ++k) {
                float ax = 0.f, ay = 0.f;
#pragma unroll
                for (int m = 0; m < 8; ++m) {
                    ax = fmaf(v[k][m].x, pq[2*m],     ax);
                    ay = fmaf(v[k][m].y, pq[2*m + 1], ay);
                }
                logit[k] += ax + ay;   // same order as pk_fma x/y chains + x+y
            }
        } else {
            if (lane < 16)
                out[(size_t)n * 512 + j * 16 + lane] = pval;
        }
    }
}

extern "C" void kernel_launch(void* const* d_in, const int* in_sizes, int n_in,
                              void* d_out, int out_size, void* d_ws, size_t ws_size,
                              hipStream_t stream) {
    const float* x = (const float*)d_in[0];
    const float* w = (const float*)d_in[1];
    float* out = (float*)d_out;
    const int nblocks = 450 * 32;   // one wave per (n, j)

    const size_t need = (size_t)(XT_ELEMS + WT_ELEMS) * sizeof(unsigned short);
    if (d_ws != nullptr && ws_size >= need) {
        unsigned short* xt = (unsigned short*)d_ws;
        unsigned short* wt = xt + XT_ELEMS;
        stage_kernel<<<(XT_ELEMS + WT_ELEMS) / 256, 256, 0, stream>>>(x, w, xt, wt);
        convcaps_kernel<true><<<nblocks, 64, 0, stream>>>(xt, wt, out);
    } else {
        convcaps_kernel<false><<<nblocks, 64, 0, stream>>>(x, w, out);
    }
}

// Round 2
// 84.353 us; speedup vs baseline: 1.0086x; 1.0086x over previous
//
#include <hip/hip_runtime.h>

// ConvCapsLayer: A=32,B=32,K=3,P=4,STRIDE=2,ITERS=3 — fp32 in/out
// x: (2,32,32,512) f32   weights: (288,32,16) f32   out: (450,512) f32
//
// R15 = R14 + occupancy push + issue cuts. One WAVE per (n, j), 64-thr
// blocks; lane owns i = lane+64k, k=0..4 (k=4 only lane<32); v[5][8]
// packed v2f in registers; bf16-staged inputs:
//   xt_bf[pixel][a][16]  (4 MB, cast)     wt_bf[j][k][lane][16] (320 KB)
// Unnormalized softmax (SE rides butterfly), split-first butterfly,
// xor1/2 on DPP, xor4/8/16 on ds_swizzle, p-broadcast via v_readlane.
// R15 changes:
//   __launch_bounds__(64,4): cap 128 VGPR -> guarantee 4 waves/SIMD
//     (live set ~95-110 post-R14; R4's spill was a tighter cap).
//   x unpack row-at-a-time (peak pressure -12 regs at k=4).
//   logit dot back to v_pk_fma (40 pk vs 80 scalar), readlane broadcast
//     kept; bit-identical chain order.
//   rcp/rsq intrinsics for s1/seR and squash (3 div + 3 sqrt -> 6 ops).
// Probed and rejected: 4-wave blocks w/ LDS x-stage (R12, +3.4µs), 2-j ILP
// (R7, neutral), recompute-v (R10, spill), DS->DPP/swizzle alone (R14,
// neutral -> cross-lane chains not critical path).
// LESSON (R4, R10): live set ~84 VGPR. Never bound/structure below it.
// Budget: dur = ~42µs harness d_ws-poison fill (81% HBM peak, untouchable)
//             + ~3.5µs staging + ~35µs main (occupancy/latency plateau).

#define OH 15
#define OW 15
#define EPS_ 1e-8f

#define XT_ELEMS (2 * 32 * 32 * 512)        // 2,097,152 bf16 (4 MB)
#define WT_ELEMS (32 * 5 * 64 * 16)         // 163,840 bf16 (320 KB)

typedef float v2f __attribute__((ext_vector_type(2)));

__device__ __forceinline__ v2f pfma(float a, v2f b, v2f c) {
    return __builtin_elementwise_fma((v2f){a, a}, b, c);
}
__device__ __forceinline__ float b_lo(unsigned int u) {
    union { unsigned int i; float f; } c; c.i = u << 16; return c.f;
}
__device__ __forceinline__ float b_hi(unsigned int u) {
    union { unsigned int i; float f; } c; c.i = u & 0xFFFF0000u; return c.f;
}
__device__ __forceinline__ unsigned short f2bf(float f) {
    union { float f; unsigned int i; } c; c.f = f;
    return (unsigned short)((c.i + 0x7FFFu + ((c.i >> 16) & 1u)) >> 16); // RNE
}

// ---- cross-lane helpers ----
// DPP quad_perm[1,0,3,2] = xor1 ; quad_perm[2,3,0,1] = xor2
__device__ __forceinline__ float dppx1(float x) {
    return __builtin_bit_cast(float, __builtin_amdgcn_update_dpp(
        0, __builtin_bit_cast(int, x), 0xB1, 0xF, 0xF, true));
}
__device__ __forceinline__ float dppx2(float x) {
    return __builtin_bit_cast(float, __builtin_amdgcn_update_dpp(
        0, __builtin_bit_cast(int, x), 0x4E, 0xF, 0xF, true));
}
// ds_swizzle BitMode: offset = (xor<<10)|(or<<5)|and, and=0x1F
template <int OFF>
__device__ __forceinline__ float swzx(float x) {
    return __builtin_bit_cast(float, __builtin_amdgcn_ds_swizzle(
        __builtin_bit_cast(int, x), OFF));
}
__device__ __forceinline__ float rdlane(float x, int q) {
    return __builtin_bit_cast(float, __builtin_amdgcn_readlane(
        __builtin_bit_cast(int, x), q));
}

// merged staging: [0, XT_ELEMS) casts x; [XT_ELEMS, +WT_ELEMS) permutes w
__global__ __launch_bounds__(256) void stage_kernel(
    const float* __restrict__ x, const float* __restrict__ w,
    unsigned short* __restrict__ xt, unsigned short* __restrict__ wt)
{
    const int tid = blockIdx.x * 256 + threadIdx.x;
    if (tid < XT_ELEMS) {
        xt[tid] = f2bf(x[tid]);
    } else {
        const int t2 = tid - XT_ELEMS;      // over WT_ELEMS
        const int j  = t2 / 5120;
        const int r  = t2 - j * 5120;
        const int k  = r >> 10;
        const int L  = (r >> 4) & 63;
        const int e  = r & 15;
        const int i  = L + 64 * k;
        wt[t2] = (i < 288) ? f2bf(w[(size_t)i * 512 + j * 16 + e])
                           : (unsigned short)0;
    }
}

template <bool PERM>
__global__ __launch_bounds__(64, 4) void convcaps_kernel(
    const void* __restrict__ xp,   // PERM ? bf16 xt : f32 x
    const void* __restrict__ wp_,  // PERM ? bf16 wt : f32 w
    float* __restrict__ out)       // (450,512)
{
    const int blk  = blockIdx.x;      // 0..14399
    const int n    = blk >> 5;        // patch 0..449
    const int j    = blk & 31;        // out capsule
    const int lane = threadIdx.x;     // 0..63

    const int batch = n / (OH * OW);
    const int rem   = n - batch * OH * OW;
    const int oy    = rem / OW;
    const int ox    = rem - oy * OW;

    const bool has5 = (lane < 32);

    v2f v[5][8];                      // v[k][p*2+qq]
    // inactive 5th slot: logit = -inf so exp -> 0 (drops has5 selects later)
    float logit[5] = {0.f, 0.f, 0.f, 0.f, has5 ? 0.f : -1e30f};

    // ---- v[k] = X_i(4x4) * W_ij(4x4), i = lane + 64k ----
#pragma unroll
    for (int k = 0; k < 5; ++k) {
        if (k == 4 && !has5) {
#pragma unroll
            for (int m = 0; m < 8; ++m) v[4][m] = (v2f){0.f, 0.f};
        } else {
            const int i  = lane + 64 * k;
            const int a  = i & 31;
            const int kw = (i >> 5) % 3;
            const int kh = i / 96;
            const int h  = oy * 2 + kh;
            const int wc = ox * 2 + kw;
            const int pixel = (batch * 32 + h) * 32 + wc;

            v2f wr2[4][2];
            if (PERM) {
                // xt[pixel][a][16] bf16: 32B contiguous per lane
                const uint4* xb = reinterpret_cast<const uint4*>(
                    (const unsigned short*)xp + ((size_t)pixel * 512 + a * 16));
                uint4 u0 = xb[0], u1 = xb[1];
                // wt[j][k][lane][16] bf16: 32B contiguous per lane
                const uint4* wb = reinterpret_cast<const uint4*>(
                    (const unsigned short*)wp_ + (((size_t)j * 5 + k) * 64 + lane) * 16);
                uint4 q0 = wb[0], q1 = wb[1];
                wr2[0][0] = (v2f){b_lo(q0.x), b_hi(q0.x)};
                wr2[0][1] = (v2f){b_lo(q0.y), b_hi(q0.y)};
                wr2[1][0] = (v2f){b_lo(q0.z), b_hi(q0.z)};
                wr2[1][1] = (v2f){b_lo(q0.w), b_hi(q0.w)};
                wr2[2][0] = (v2f){b_lo(q1.x), b_hi(q1.x)};
                wr2[2][1] = (v2f){b_lo(q1.y), b_hi(q1.y)};
                wr2[3][0] = (v2f){b_lo(q1.z), b_hi(q1.z)};
                wr2[3][1] = (v2f){b_lo(q1.w), b_hi(q1.w)};
                // row-at-a-time unpack: only 4 x-floats live at once
                const unsigned int dwp[8] = {u0.x, u0.y, u0.z, u0.w,
                                             u1.x, u1.y, u1.z, u1.w};
#pragma unroll
                for (int p = 0; p < 4; ++p) {
                    const unsigned int da = dwp[2*p], db = dwp[2*p+1];
                    const float x0 = b_lo(da), x1 = b_hi(da);
                    const float x2 = b_lo(db), x3 = b_hi(db);
#pragma unroll
                    for (int qq = 0; qq < 2; ++qq) {
                        v2f acc = (v2f){0.f, 0.f};
                        acc = pfma(x0, wr2[0][qq], acc);
                        acc = pfma(x1, wr2[1][qq], acc);
                        acc = pfma(x2, wr2[2][qq], acc);
                        acc = pfma(x3, wr2[3][qq], acc);
                        v[k][p*2+qq] = acc;
                    }
                }
            } else {
                const float4* xv = reinterpret_cast<const float4*>(
                    (const float*)xp + ((size_t)pixel * 512 + a * 16));
                const float4* wq = reinterpret_cast<const float4*>(
                    (const float*)wp_ + ((size_t)i * 32 + j) * 16);
                float4 w0 = wq[0], w1 = wq[1], w2 = wq[2], w3 = wq[3];
                wr2[0][0]=(v2f){w0.x,w0.y}; wr2[0][1]=(v2f){w0.z,w0.w};
                wr2[1][0]=(v2f){w1.x,w1.y}; wr2[1][1]=(v2f){w1.z,w1.w};
                wr2[2][0]=(v2f){w2.x,w2.y}; wr2[2][1]=(v2f){w2.z,w2.w};
                wr2[3][0]=(v2f){w3.x,w3.y}; wr2[3][1]=(v2f){w3.z,w3.w};
#pragma unroll
                for (int p = 0; p < 4; ++p) {
                    float4 xr4 = xv[p];
#pragma unroll
                    for (int qq = 0; qq < 2; ++qq) {
                        v2f acc = (v2f){0.f, 0.f};
                        acc = pfma(xr4.x, wr2[0][qq], acc);
                        acc = pfma(xr4.y, wr2[1][qq], acc);
                        acc = pfma(xr4.z, wr2[2][qq], acc);
                        acc = pfma(xr4.w, wr2[3][qq], acc);
                        v[k][p*2+qq] = acc;
                    }
                }
            }
        }
    }

#pragma unroll
    for (int it = 0; it < 3; ++it) {
        v2f c2[8];
        float se_loc;
        if (it == 0) {
#pragma unroll
            for (int m = 0; m < 8; ++m)
                c2[m] = v[0][m] + v[1][m] + v[2][m] + v[3][m] + v[4][m];
            se_loc = 0.f;  // normalizer is 288 (softmax of zeros)
        } else {
            const float e0 = __expf(logit[0]), e1 = __expf(logit[1]);
            const float e2 = __expf(logit[2]), e3 = __expf(logit[3]);
            const float e4 = __expf(logit[4]);   // 0 for lanes >= 32
#pragma unroll
            for (int m = 0; m < 8; ++m)
                c2[m] = pfma(e0, v[0][m],
                        pfma(e1, v[1][m],
                        pfma(e2, v[2][m],
                        pfma(e3, v[3][m],
                        pfma(e4, v[4][m], (v2f){0.f, 0.f})))));
            se_loc = e0 + e1 + e2 + e3 + e4;
        }

        float c[16];
#pragma unroll
        for (int m = 0; m < 8; ++m) { c[2*m] = c2[m].x; c[2*m+1] = c2[m].y; }

        // ---- split-first butterfly: comp bit b -> lane bit b ----
        float seR = se_loc;
        float s8[8];
        {
            const bool b = lane & 1;
#pragma unroll
            for (int m = 0; m < 8; ++m) {
                float send = b ? c[2*m]   : c[2*m+1];
                float keep = b ? c[2*m+1] : c[2*m];
                s8[m] = keep + dppx1(send);
            }
            if (it > 0) seR += dppx1(seR);
        }
        float s4[4];
        {
            const bool b = (lane >> 1) & 1;
#pragma unroll
            for (int m = 0; m < 4; ++m) {
                float send = b ? s8[2*m]   : s8[2*m+1];
                float keep = b ? s8[2*m+1] : s8[2*m];
                s4[m] = keep + dppx2(send);
            }
            if (it > 0) seR += dppx2(seR);
        }
        float s2v[2];
        {
            const bool b = (lane >> 2) & 1;
#pragma unroll
            for (int m = 0; m < 2; ++m) {
                float send = b ? s4[2*m]   : s4[2*m+1];
                float keep = b ? s4[2*m+1] : s4[2*m];
                s2v[m] = keep + swzx<0x101F>(send);
            }
            if (it > 0) seR += swzx<0x101F>(seR);
        }
        float s1;
        {
            const bool b = (lane >> 3) & 1;
            float send = b ? s2v[0] : s2v[1];
            float keep = b ? s2v[1] : s2v[0];
            s1 = keep + swzx<0x201F>(send);
            if (it > 0) seR += swzx<0x201F>(seR);
        }
        s1 += swzx<0x401F>(s1);    if (it > 0) seR += swzx<0x401F>(seR);
        s1 += __shfl_xor(s1, 32);  if (it > 0) seR += __shfl_xor(seR, 32);
        // s1 = sum_i (e_i or 1) * v_i[comp], comp = lane&15 ; seR = SE

        const float s = (it == 0) ? s1 * (1.0f / 288.0f)
                                  : s1 * __builtin_amdgcn_rcpf(seR);

        // ---- squash ----
        float t2 = s * s;
        t2 += dppx1(t2);
        t2 += dppx2(t2);
        t2 += swzx<0x101F>(t2);
        t2 += swzx<0x201F>(t2);
        const float n2 = t2;
        const float scale = n2 * __builtin_amdgcn_rcpf(1.0f + n2)
                               * __builtin_amdgcn_rsqf(n2 + EPS_);
        const float pval = s * scale;   // comp (lane&15) of p

        if (it < 2) {
            // p[q] identical at lanes q, q+16, q+32, q+48 -> readlane(q)
            // broadcast; dot in packed v_pk_fma (acc.x = even chain,
            // acc.y = odd chain — same order as scalar version).
            v2f pq2[8];
#pragma unroll
            for (int m = 0; m < 8; ++m)
                pq2[m] = (v2f){rdlane(pval, 2*m), rdlane(pval, 2*m+1)};
#pragma unroll
            for (int k = 0; k < 5; ++k) {
                v2f acc = (v2f){0.f, 0.f};
#pragma unroll
                for (int m = 0; m < 8; ++m)
                    acc = __builtin_elementwise_fma(v[k][m], pq2[m], acc);
                logit[k] += acc.x + acc.y;
            }
        } else {
            if (lane < 16)
                out[(size_t)n * 512 + j * 16 + lane] = pval;
        }
    }
}

extern "C" void kernel_launch(void* const* d_in, const int* in_sizes, int n_in,
                              void* d_out, int out_size, void* d_ws, size_t ws_size,
                              hipStream_t stream) {
    const float* x = (const float*)d_in[0];
    const float* w = (const float*)d_in[1];
    float* out = (float*)d_out;
    const int nblocks = 450 * 32;   // one wave per (n, j)

    const size_t need = (size_t)(XT_ELEMS + WT_ELEMS) * sizeof(unsigned short);
    if (d_ws != nullptr && ws_size >= need) {
        unsigned short* xt = (unsigned short*)d_ws;
        unsigned short* wt = xt + XT_ELEMS;
        stage_kernel<<<(XT_ELEMS + WT_ELEMS) / 256, 256, 0, stream>>>(x, w, xt, wt);
        convcaps_kernel<true><<<nblocks, 64, 0, stream>>>(xt, wt, out);
    } else {
        convcaps_kernel<false><<<nblocks, 64, 0, stream>>>(x, w, out);
    }
}

// Round 3
// 82.929 us; speedup vs baseline: 1.0260x; 1.0172x over previous
//
#include <hip/hip_runtime.h>

// ConvCapsLayer: A=32,B=32,K=3,P=4,STRIDE=2,ITERS=3 — fp32 in/out
// x: (2,32,32,512) f32   weights: (288,32,16) f32   out: (450,512) f32
//
// R16 = R15 + XCD-aware work swizzle (T1). One WAVE per (n, j), 64-thr
// blocks; lane owns i = lane+64k, k=0..4 (k=4 only lane<32); v[5][8]
// packed v2f in registers; bf16-staged inputs:
//   xt_bf[pixel][a][16]  (4 MB, cast)     wt_bf[j][k][lane][16] (320 KB)
// Unnormalized softmax (SE rides butterfly), split-first butterfly,
// xor1/2 on DPP, xor4/8/16 on ds_swizzle, p-broadcast via v_readlane.
// R16 change: blk = n*32+j round-robins XCDs by j&7 -> EVERY XCD streams
//   the whole 4MB xt (== entire per-XCD L2) -> continuous L2 thrash, all
//   loads from L3. Remap wid=(blk&7)*1800+(blk>>3): each XCD owns a
//   contiguous n-chunk (~0.6MB working set, L2-resident). Bijective
//   (14400%8==0). Pure index permutation, bit-identical output.
// Probed and rejected: 4-wave blocks w/ LDS x-stage (R12, +3.4µs), 2-j ILP
// (R7, neutral), recompute-v (R10, spill), DS->DPP/swizzle (R14, neutral),
// occupancy cap (64,4) (R15, ~neutral; kept — no spill, no downside).
// LESSON (R4, R10): live set ~84 VGPR. Never bound/structure below it.
// LESSON (R14/R15): main kernel insensitive to issue count & xlane latency
//   -> stall is memory-system, not pipeline.
// Budget: dur = ~42µs harness d_ws-poison fill (81% HBM peak, untouchable)
//             + ~2.5µs staging + main.

#define OH 15
#define OW 15
#define EPS_ 1e-8f

#define XT_ELEMS (2 * 32 * 32 * 512)        // 2,097,152 bf16 (4 MB)
#define WT_ELEMS (32 * 5 * 64 * 16)         // 163,840 bf16 (320 KB)

typedef float v2f __attribute__((ext_vector_type(2)));

__device__ __forceinline__ v2f pfma(float a, v2f b, v2f c) {
    return __builtin_elementwise_fma((v2f){a, a}, b, c);
}
__device__ __forceinline__ float b_lo(unsigned int u) {
    union { unsigned int i; float f; } c; c.i = u << 16; return c.f;
}
__device__ __forceinline__ float b_hi(unsigned int u) {
    union { unsigned int i; float f; } c; c.i = u & 0xFFFF0000u; return c.f;
}
__device__ __forceinline__ unsigned short f2bf(float f) {
    union { float f; unsigned int i; } c; c.f = f;
    return (unsigned short)((c.i + 0x7FFFu + ((c.i >> 16) & 1u)) >> 16); // RNE
}

// ---- cross-lane helpers ----
// DPP quad_perm[1,0,3,2] = xor1 ; quad_perm[2,3,0,1] = xor2
__device__ __forceinline__ float dppx1(float x) {
    return __builtin_bit_cast(float, __builtin_amdgcn_update_dpp(
        0, __builtin_bit_cast(int, x), 0xB1, 0xF, 0xF, true));
}
__device__ __forceinline__ float dppx2(float x) {
    return __builtin_bit_cast(float, __builtin_amdgcn_update_dpp(
        0, __builtin_bit_cast(int, x), 0x4E, 0xF, 0xF, true));
}
// ds_swizzle BitMode: offset = (xor<<10)|(or<<5)|and, and=0x1F
template <int OFF>
__device__ __forceinline__ float swzx(float x) {
    return __builtin_bit_cast(float, __builtin_amdgcn_ds_swizzle(
        __builtin_bit_cast(int, x), OFF));
}
__device__ __forceinline__ float rdlane(float x, int q) {
    return __builtin_bit_cast(float, __builtin_amdgcn_readlane(
        __builtin_bit_cast(int, x), q));
}

// merged staging: [0, XT_ELEMS) casts x; [XT_ELEMS, +WT_ELEMS) permutes w
__global__ __launch_bounds__(256) void stage_kernel(
    const float* __restrict__ x, const float* __restrict__ w,
    unsigned short* __restrict__ xt, unsigned short* __restrict__ wt)
{
    const int tid = blockIdx.x * 256 + threadIdx.x;
    if (tid < XT_ELEMS) {
        xt[tid] = f2bf(x[tid]);
    } else {
        const int t2 = tid - XT_ELEMS;      // over WT_ELEMS
        const int j  = t2 / 5120;
        const int r  = t2 - j * 5120;
        const int k  = r >> 10;
        const int L  = (r >> 4) & 63;
        const int e  = r & 15;
        const int i  = L + 64 * k;
        wt[t2] = (i < 288) ? f2bf(w[(size_t)i * 512 + j * 16 + e])
                           : (unsigned short)0;
    }
}

template <bool PERM>
__global__ __launch_bounds__(64, 4) void convcaps_kernel(
    const void* __restrict__ xp,   // PERM ? bf16 xt : f32 x
    const void* __restrict__ wp_,  // PERM ? bf16 wt : f32 w
    float* __restrict__ out)       // (450,512)
{
    // XCD-aware swizzle: XCD = blk&7 (round-robin). Give each XCD a
    // contiguous n-major work chunk of 1800 so its L2 working set is
    // ~0.6MB (L2-resident) instead of the full 4MB xt.
    const int blk  = blockIdx.x;              // 0..14399
    const int wid  = (blk & 7) * 1800 + (blk >> 3);
    const int n    = wid >> 5;                // patch 0..449
    const int j    = wid & 31;                // out capsule
    const int lane = threadIdx.x;             // 0..63

    const int batch = n / (OH * OW);
    const int rem   = n - batch * OH * OW;
    const int oy    = rem / OW;
    const int ox    = rem - oy * OW;

    const bool has5 = (lane < 32);

    v2f v[5][8];                      // v[k][p*2+qq]
    // inactive 5th slot: logit = -inf so exp -> 0 (drops has5 selects later)
    float logit[5] = {0.f, 0.f, 0.f, 0.f, has5 ? 0.f : -1e30f};

    // ---- v[k] = X_i(4x4) * W_ij(4x4), i = lane + 64k ----
#pragma unroll
    for (int k = 0; k < 5; ++k) {
        if (k == 4 && !has5) {
#pragma unroll
            for (int m = 0; m < 8; ++m) v[4][m] = (v2f){0.f, 0.f};
        } else {
            const int i  = lane + 64 * k;
            const int a  = i & 31;
            const int kw = (i >> 5) % 3;
            const int kh = i / 96;
            const int h  = oy * 2 + kh;
            const int wc = ox * 2 + kw;
            const int pixel = (batch * 32 + h) * 32 + wc;

            v2f wr2[4][2];
            if (PERM) {
                // xt[pixel][a][16] bf16: 32B contiguous per lane
                const uint4* xb = reinterpret_cast<const uint4*>(
                    (const unsigned short*)xp + ((size_t)pixel * 512 + a * 16));
                uint4 u0 = xb[0], u1 = xb[1];
                // wt[j][k][lane][16] bf16: 32B contiguous per lane
                const uint4* wb = reinterpret_cast<const uint4*>(
                    (const unsigned short*)wp_ + (((size_t)j * 5 + k) * 64 + lane) * 16);
                uint4 q0 = wb[0], q1 = wb[1];
                wr2[0][0] = (v2f){b_lo(q0.x), b_hi(q0.x)};
                wr2[0][1] = (v2f){b_lo(q0.y), b_hi(q0.y)};
                wr2[1][0] = (v2f){b_lo(q0.z), b_hi(q0.z)};
                wr2[1][1] = (v2f){b_lo(q0.w), b_hi(q0.w)};
                wr2[2][0] = (v2f){b_lo(q1.x), b_hi(q1.x)};
                wr2[2][1] = (v2f){b_lo(q1.y), b_hi(q1.y)};
                wr2[3][0] = (v2f){b_lo(q1.z), b_hi(q1.z)};
                wr2[3][1] = (v2f){b_lo(q1.w), b_hi(q1.w)};
                // row-at-a-time unpack: only 4 x-floats live at once
                const unsigned int dwp[8] = {u0.x, u0.y, u0.z, u0.w,
                                             u1.x, u1.y, u1.z, u1.w};
#pragma unroll
                for (int p = 0; p < 4; ++p) {
                    const unsigned int da = dwp[2*p], db = dwp[2*p+1];
                    const float x0 = b_lo(da), x1 = b_hi(da);
                    const float x2 = b_lo(db), x3 = b_hi(db);
#pragma unroll
                    for (int qq = 0; qq < 2; ++qq) {
                        v2f acc = (v2f){0.f, 0.f};
                        acc = pfma(x0, wr2[0][qq], acc);
                        acc = pfma(x1, wr2[1][qq], acc);
                        acc = pfma(x2, wr2[2][qq], acc);
                        acc = pfma(x3, wr2[3][qq], acc);
                        v[k][p*2+qq] = acc;
                    }
                }
            } else {
                const float4* xv = reinterpret_cast<const float4*>(
                    (const float*)xp + ((size_t)pixel * 512 + a * 16));
                const float4* wq = reinterpret_cast<const float4*>(
                    (const float*)wp_ + ((size_t)i * 32 + j) * 16);
                float4 w0 = wq[0], w1 = wq[1], w2 = wq[2], w3 = wq[3];
                wr2[0][0]=(v2f){w0.x,w0.y}; wr2[0][1]=(v2f){w0.z,w0.w};
                wr2[1][0]=(v2f){w1.x,w1.y}; wr2[1][1]=(v2f){w1.z,w1.w};
                wr2[2][0]=(v2f){w2.x,w2.y}; wr2[2][1]=(v2f){w2.z,w2.w};
                wr2[3][0]=(v2f){w3.x,w3.y}; wr2[3][1]=(v2f){w3.z,w3.w};
#pragma unroll
                for (int p = 0; p < 4; ++p) {
                    float4 xr4 = xv[p];
#pragma unroll
                    for (int qq = 0; qq < 2; ++qq) {
                        v2f acc = (v2f){0.f, 0.f};
                        acc = pfma(xr4.x, wr2[0][qq], acc);
                        acc = pfma(xr4.y, wr2[1][qq], acc);
                        acc = pfma(xr4.z, wr2[2][qq], acc);
                        acc = pfma(xr4.w, wr2[3][qq], acc);
                        v[k][p*2+qq] = acc;
                    }
                }
            }
        }
    }

#pragma unroll
    for (int it = 0; it < 3; ++it) {
        v2f c2[8];
        float se_loc;
        if (it == 0) {
#pragma unroll
            for (int m = 0; m < 8; ++m)
                c2[m] = v[0][m] + v[1][m] + v[2][m] + v[3][m] + v[4][m];
            se_loc = 0.f;  // normalizer is 288 (softmax of zeros)
        } else {
            const float e0 = __expf(logit[0]), e1 = __expf(logit[1]);
            const float e2 = __expf(logit[2]), e3 = __expf(logit[3]);
            const float e4 = __expf(logit[4]);   // 0 for lanes >= 32
#pragma unroll
            for (int m = 0; m < 8; ++m)
                c2[m] = pfma(e0, v[0][m],
                        pfma(e1, v[1][m],
                        pfma(e2, v[2][m],
                        pfma(e3, v[3][m],
                        pfma(e4, v[4][m], (v2f){0.f, 0.f})))));
            se_loc = e0 + e1 + e2 + e3 + e4;
        }

        float c[16];
#pragma unroll
        for (int m = 0; m < 8; ++m) { c[2*m] = c2[m].x; c[2*m+1] = c2[m].y; }

        // ---- split-first butterfly: comp bit b -> lane bit b ----
        float seR = se_loc;
        float s8[8];
        {
            const bool b = lane & 1;
#pragma unroll
            for (int m = 0; m < 8; ++m) {
                float send = b ? c[2*m]   : c[2*m+1];
                float keep = b ? c[2*m+1] : c[2*m];
                s8[m] = keep + dppx1(send);
            }
            if (it > 0) seR += dppx1(seR);
        }
        float s4[4];
        {
            const bool b = (lane >> 1) & 1;
#pragma unroll
            for (int m = 0; m < 4; ++m) {
                float send = b ? s8[2*m]   : s8[2*m+1];
                float keep = b ? s8[2*m+1] : s8[2*m];
                s4[m] = keep + dppx2(send);
            }
            if (it > 0) seR += dppx2(seR);
        }
        float s2v[2];
        {
            const bool b = (lane >> 2) & 1;
#pragma unroll
            for (int m = 0; m < 2; ++m) {
                float send = b ? s4[2*m]   : s4[2*m+1];
                float keep = b ? s4[2*m+1] : s4[2*m];
                s2v[m] = keep + swzx<0x101F>(send);
            }
            if (it > 0) seR += swzx<0x101F>(seR);
        }
        float s1;
        {
            const bool b = (lane >> 3) & 1;
            float send = b ? s2v[0] : s2v[1];
            float keep = b ? s2v[1] : s2v[0];
            s1 = keep + swzx<0x201F>(send);
            if (it > 0) seR += swzx<0x201F>(seR);
        }
        s1 += swzx<0x401F>(s1);    if (it > 0) seR += swzx<0x401F>(seR);
        s1 += __shfl_xor(s1, 32);  if (it > 0) seR += __shfl_xor(seR, 32);
        // s1 = sum_i (e_i or 1) * v_i[comp], comp = lane&15 ; seR = SE

        const float s = (it == 0) ? s1 * (1.0f / 288.0f)
                                  : s1 * __builtin_amdgcn_rcpf(seR);

        // ---- squash ----
        float t2 = s * s;
        t2 += dppx1(t2);
        t2 += dppx2(t2);
        t2 += swzx<0x101F>(t2);
        t2 += swzx<0x201F>(t2);
        const float n2 = t2;
        const float scale = n2 * __builtin_amdgcn_rcpf(1.0f + n2)
                               * __builtin_amdgcn_rsqf(n2 + EPS_);
        const float pval = s * scale;   // comp (lane&15) of p

        if (it < 2) {
            // p[q] identical at lanes q, q+16, q+32, q+48 -> readlane(q)
            // broadcast; dot in packed v_pk_fma (acc.x = even chain,
            // acc.y = odd chain — same order as scalar version).
            v2f pq2[8];
#pragma unroll
            for (int m = 0; m < 8; ++m)
                pq2[m] = (v2f){rdlane(pval, 2*m), rdlane(pval, 2*m+1)};
#pragma unroll
            for (int k = 0; k < 5; ++k) {
                v2f acc = (v2f){0.f, 0.f};
#pragma unroll
                for (int m = 0; m < 8; ++m)
                    acc = __builtin_elementwise_fma(v[k][m], pq2[m], acc);
                logit[k] += acc.x + acc.y;
            }
        } else {
            if (lane < 16)
                out[(size_t)n * 512 + j * 16 + lane] = pval;
        }
    }
}

extern "C" void kernel_launch(void* const* d_in, const int* in_sizes, int n_in,
                              void* d_out, int out_size, void* d_ws, size_t ws_size,
                              hipStream_t stream) {
    const float* x = (const float*)d_in[0];
    const float* w = (const float*)d_in[1];
    float* out = (float*)d_out;
    const int nblocks = 450 * 32;   // one wave per (n, j)

    const size_t need = (size_t)(XT_ELEMS + WT_ELEMS) * sizeof(unsigned short);
    if (d_ws != nullptr && ws_size >= need) {
        unsigned short* xt = (unsigned short*)d_ws;
        unsigned short* wt = xt + XT_ELEMS;
        stage_kernel<<<(XT_ELEMS + WT_ELEMS) / 256, 256, 0, stream>>>(x, w, xt, wt);
        convcaps_kernel<true><<<nblocks, 64, 0, stream>>>(xt, wt, out);
    } else {
        convcaps_kernel<false><<<nblocks, 64, 0, stream>>>(x, w, out);
    }
}